// Round 1
// baseline (554.830 us; speedup 1.0000x reference)
//
#include <hip/hip_runtime.h>

typedef __bf16 bf16x8 __attribute__((ext_vector_type(8)));
typedef float  f32x4  __attribute__((ext_vector_type(4)));
typedef unsigned short u16;
typedef u16 u16x8 __attribute__((ext_vector_type(8)));

__device__ __forceinline__ u16 f2bf(float f) {
    unsigned u = __builtin_bit_cast(unsigned, f);
    return (u16)((u + 0x7FFFu + ((u >> 16) & 1u)) >> 16);  // RNE
}

__device__ __forceinline__ bf16x8 cvt8(const float* __restrict__ p) {
    f32x4 v0 = *(const f32x4*)p;
    f32x4 v1 = *(const f32x4*)(p + 4);
    u16x8 h;
    h[0]=f2bf(v0[0]); h[1]=f2bf(v0[1]); h[2]=f2bf(v0[2]); h[3]=f2bf(v0[3]);
    h[4]=f2bf(v1[0]); h[5]=f2bf(v1[1]); h[6]=f2bf(v1[2]); h[7]=f2bf(v1[3]);
    return __builtin_bit_cast(bf16x8, h);
}

__device__ __forceinline__ bf16x8 cvt8_guard(const float* __restrict__ p, int valid) {
    u16x8 h;
#pragma unroll
    for (int j = 0; j < 8; ++j) h[j] = (j < valid) ? f2bf(p[j]) : (u16)0;
    return __builtin_bit_cast(bf16x8, h);
}

// ---------------------------------------------------------------------------
// Gather + transpose + fp32->bf16: Bt[n][k] = bf16(feats[idx[k]][n]), zero-pad
// k in [Kcnt, Kpad). Reads coalesced (128 consecutive lanes = one feature row).
// ---------------------------------------------------------------------------
__global__ __launch_bounds__(256) void gather_bt(
    const float* __restrict__ feats, const int* __restrict__ idx,
    u16* __restrict__ Bt, int Kcnt, int Kpad)
{
    int g = blockIdx.x * 256 + threadIdx.x;
    if (g >= Kpad * 128) return;
    int n = g & 127;
    int k = g >> 7;
    u16 v = 0;
    if (k < Kcnt) v = f2bf(feats[(size_t)idx[k] * 128 + n]);
    Bt[(size_t)n * Kpad + k] = v;
}

// ---------------------------------------------------------------------------
// Split-K GEMM: C[M][128] += A[M][K](f32) * B(bf16, Bt[128][Kpad] layout).
// Workgroup: 4 waves, each wave 32 rows x 128 cols via 16x16x32 bf16 MFMA.
// grid = (ceil(M/128), KSPLIT); fp32 atomicAdd epilogue (C pre-zeroed).
// ---------------------------------------------------------------------------
__global__ __launch_bounds__(256) void gemm_bt(
    const float* __restrict__ A, const u16* __restrict__ Bt,
    float* __restrict__ C, int M, int K, int Kpad, int steps_per_split)
{
    const int wid  = threadIdx.x >> 6;
    const int lane = threadIdx.x & 63;
    const int l15  = lane & 15;
    const int lhi  = lane >> 4;

    const int row0 = blockIdx.x * 128 + wid * 32;
    const int total_steps = (K + 31) >> 5;
    int s0 = blockIdx.y * steps_per_split;
    int s1 = s0 + steps_per_split;
    if (s1 > total_steps) s1 = total_steps;
    if (s0 >= s1) return;

    f32x4 acc[2][8];
#pragma unroll
    for (int i = 0; i < 2; ++i)
#pragma unroll
        for (int j = 0; j < 8; ++j) acc[i][j] = (f32x4){0.f, 0.f, 0.f, 0.f};

    // A rows for the two 16-row fragments (clamped so tail blocks stay in-bounds;
    // their garbage results are discarded by the r<M store guard).
    const int rA0 = min(row0 + l15,      M - 1);
    const int rA1 = min(row0 + 16 + l15, M - 1);
    const float* __restrict__ a0p = A + (size_t)rA0 * K;
    const float* __restrict__ a1p = A + (size_t)rA1 * K;

    // B base for this lane: col = l15 (+16*cf later), k-offset lhi*8 (+k0 later)
    const u16* __restrict__ btl = Bt + (size_t)l15 * Kpad + lhi * 8;

    for (int s = s0; s < s1; ++s) {
        const int k0   = s << 5;
        const int koff = k0 + lhi * 8;

        bf16x8 af[2];
        if (k0 + 32 <= K) {              // uniform fast path
            af[0] = cvt8(a0p + koff);
            af[1] = cvt8(a1p + koff);
        } else {                          // final partial k-step only
            af[0] = cvt8_guard(a0p + koff, K - koff);
            af[1] = cvt8_guard(a1p + koff, K - koff);
        }

        bf16x8 bfr[8];
#pragma unroll
        for (int cf = 0; cf < 8; ++cf)
            bfr[cf] = __builtin_bit_cast(bf16x8,
                *(const u16x8*)(btl + (size_t)cf * 16 * Kpad + k0));

#pragma unroll
        for (int cf = 0; cf < 8; ++cf) {
            acc[0][cf] = __builtin_amdgcn_mfma_f32_16x16x32_bf16(af[0], bfr[cf], acc[0][cf], 0, 0, 0);
            acc[1][cf] = __builtin_amdgcn_mfma_f32_16x16x32_bf16(af[1], bfr[cf], acc[1][cf], 0, 0, 0);
        }
    }

    // Epilogue: C/D layout col = lane&15, row = (lane>>4)*4 + i  [m89-verified]
#pragma unroll
    for (int rf = 0; rf < 2; ++rf)
#pragma unroll
        for (int cf = 0; cf < 8; ++cf)
#pragma unroll
            for (int i = 0; i < 4; ++i) {
                int r = row0 + rf * 16 + lhi * 4 + i;
                if (r < M)
                    atomicAdd(C + (size_t)r * 128 + cf * 16 + l15, acc[rf][cf][i]);
            }
}

// ---------------------------------------------------------------------------
// out[M][128] = relu(concat(agg[M][128], fsrc[didx[m]][128]) @ w[256][128])
// Block: 256 threads, 32 rows. Concat staged in LDS (stride 257: conflict-free
// broadcast groups). Thread computes 2 rows x 8 cols in fp32.
// ---------------------------------------------------------------------------
__global__ __launch_bounds__(256) void dense_relu(
    const float* __restrict__ agg, const float* __restrict__ fsrc,
    const int* __restrict__ didx, const float* __restrict__ w,
    float* __restrict__ out, int M)
{
    __shared__ float sb[32][257];
    const int tid  = threadIdx.x;
    const int row0 = blockIdx.x * 32;

    for (int i = tid; i < 32 * 32; i += 256) {           // agg half
        int r = i >> 5, c4 = (i & 31) << 2;
        int gr = row0 + r;
        f32x4 v = (f32x4){0.f, 0.f, 0.f, 0.f};
        if (gr < M) v = *(const f32x4*)(agg + (size_t)gr * 128 + c4);
        sb[r][c4 + 0] = v[0]; sb[r][c4 + 1] = v[1];
        sb[r][c4 + 2] = v[2]; sb[r][c4 + 3] = v[3];
    }
    for (int i = tid; i < 32 * 32; i += 256) {           // gathered dst half
        int r = i >> 5, c4 = (i & 31) << 2;
        int gr = row0 + r;
        int sr = (gr < M) ? didx[gr] : 0;
        f32x4 v = *(const f32x4*)(fsrc + (size_t)sr * 128 + c4);
        sb[r][128 + c4 + 0] = v[0]; sb[r][128 + c4 + 1] = v[1];
        sb[r][128 + c4 + 2] = v[2]; sb[r][128 + c4 + 3] = v[3];
    }
    __syncthreads();

    const int colg = (tid & 15) << 3;   // 8-col slab
    const int r0l  = (tid >> 4) * 2;    // 2 rows
    float acc0[8], acc1[8];
#pragma unroll
    for (int c = 0; c < 8; ++c) { acc0[c] = 0.f; acc1[c] = 0.f; }

    for (int j = 0; j < 256; ++j) {
        f32x4 wa = *(const f32x4*)(w + j * 128 + colg);
        f32x4 wb = *(const f32x4*)(w + j * 128 + colg + 4);
        float a0 = sb[r0l][j];
        float a1 = sb[r0l + 1][j];
#pragma unroll
        for (int c = 0; c < 4; ++c) {
            acc0[c]     += a0 * wa[c];  acc0[c + 4] += a0 * wb[c];
            acc1[c]     += a1 * wa[c];  acc1[c + 4] += a1 * wb[c];
        }
    }

    int gr0 = row0 + r0l;
    if (gr0 < M) {
#pragma unroll
        for (int c = 0; c < 8; ++c)
            out[(size_t)gr0 * 128 + colg + c] = fmaxf(acc0[c], 0.f);
    }
    int gr1 = gr0 + 1;
    if (gr1 < M) {
#pragma unroll
        for (int c = 0; c < 8; ++c)
            out[(size_t)gr1 * 128 + colg + c] = fmaxf(acc1[c], 0.f);
    }
}

// ---------------------------------------------------------------------------
extern "C" void kernel_launch(void* const* d_in, const int* in_sizes, int n_in,
                              void* d_out, int out_size, void* d_ws, size_t ws_size,
                              hipStream_t stream)
{
    const float* src_nodes = (const float*)d_in[0];
    const int*   s1idx     = (const int*)d_in[1];
    const int*   s2idx     = (const int*)d_in[2];
    const int*   d1idx     = (const int*)d_in[3];
    const int*   d2idx     = (const int*)d_in[4];
    const float* dif1      = (const float*)d_in[5];
    const float* dif2      = (const float*)d_in[6];
    const float* w1        = (const float*)d_in[7];
    const float* w2        = (const float*)d_in[8];
    float*       out       = (float*)d_out;

    const int S2 = 16000, M2 = 4000, S1 = 3500, M1 = 1024;
    const int K2 = 16000, K1 = 3500;
    const int Kpad2 = 16000;                 // multiple of 32
    const int Kpad1 = 3520;                  // 3500 padded to 32

    char* ws = (char*)d_ws;
    size_t off = 0;
    float* agg2 = (float*)(ws + off); off += (size_t)M2 * 128 * 4;   // 2,048,000
    float* agg1 = (float*)(ws + off); off += (size_t)M1 * 128 * 4;   //   524,288
    float* x    = (float*)(ws + off); off += (size_t)M2 * 128 * 4;   // 2,048,000
    u16*   Bt2  = (u16*)(ws + off);   off += (size_t)128 * Kpad2 * 2;// 4,096,000
    u16*   Bt1  = (u16*)(ws + off);   off += (size_t)128 * Kpad1 * 2;//   901,120

    // zero both accumulators (agg2 and agg1 are contiguous)
    hipMemsetAsync(agg2, 0, (size_t)(M2 + M1) * 128 * 4, stream);

    // ---- hop 2 ----
    gather_bt<<<(Kpad2 * 128 + 255) / 256, 256, 0, stream>>>(src_nodes, s2idx, Bt2, S2, Kpad2);

    {
        const int total_steps = (K2 + 31) >> 5;            // 500
        const int ksplit = 8;                              // 32 x 8 = 256 blocks
        const int sps = (total_steps + ksplit - 1) / ksplit; // 63
        dim3 grid((M2 + 127) / 128, ksplit);
        gemm_bt<<<grid, 256, 0, stream>>>(dif2, Bt2, agg2, M2, K2, Kpad2, sps);
    }

    dense_relu<<<(M2 + 31) / 32, 256, 0, stream>>>(agg2, src_nodes, d2idx, w1, x, M2);

    // ---- hop 1 ----
    gather_bt<<<(Kpad1 * 128 + 255) / 256, 256, 0, stream>>>(x, s1idx, Bt1, S1, Kpad1);

    {
        const int total_steps = (K1 + 31) >> 5;            // 110
        const int ksplit = 32;                             // 8 x 32 = 256 blocks
        const int sps = (total_steps + ksplit - 1) / ksplit; // 4
        dim3 grid((M1 + 127) / 128, ksplit);
        gemm_bt<<<grid, 256, 0, stream>>>(dif1, Bt1, agg1, M1, K1, Kpad1, sps);
    }

    dense_relu<<<(M1 + 31) / 32, 256, 0, stream>>>(agg1, x, d1idx, w2, out, M1);
}